// Round 3
// baseline (11202.756 us; speedup 1.0000x reference)
//
#include <hip/hip_runtime.h>

typedef __attribute__((ext_vector_type(8))) short bf16x8;
typedef __attribute__((ext_vector_type(4))) float f32x4;

union FU { unsigned int u[4]; uint4 q; bf16x8 v; };

__device__ inline unsigned int cvt_pk(float lo, float hi) {
    unsigned int r;
    asm("v_cvt_pk_bf16_f32 %0, %1, %2" : "=v"(r) : "v"(lo), "v"(hi));
    return r;
}

// tanh(x) = 1 - 2/(e^{2x}+1); inf/underflow saturate to +-1 correctly.
__device__ inline float tanh_fast(float x) {
    float e = __expf(x + x);
    return fmaf(-2.f, __builtin_amdgcn_rcpf(e + 1.f), 1.f);
}

#define TS 1000
#define NEV ((TS - 1) * 4)
#define ROWB 528   // 256 bf16 = 512B + 16B pad -> per-thread const addrs, even banks

// 512 threads = 8 waves own 16 batch rows for the whole rollout.
// Per eval: [combine prev k (1 LDS b128 + 3 add), RK4 in regs]
//           [stage A: h1 = tanh(W1aug @ [yh;yl;1]) via 2 mfma -> LDS bf16, padded rows]
//           barrier
//           [stage B: h2pre = W2^T.h1^T + b2 via 16 mfma (immediate-offset ds_reads);
//            tanh; W3 partials; shfl-reduce; 3 LDS atomicAdd into ping-pong kbuf]
//           barrier
__global__ __launch_bounds__(512, 4)
void node_ode_kernel(const float* __restrict__ Ig, const float* __restrict__ tg,
                     const float* __restrict__ W1g, const float* __restrict__ b1g,
                     const float* __restrict__ W2g, const float* __restrict__ b2g,
                     const float* __restrict__ W3g, const float* __restrict__ b3g,
                     float* __restrict__ outp)
{
    __shared__ __align__(16) char h1s[16 * ROWB];  // 8448 B
    __shared__ float w3s[256 * 3];                 // 3 KiB
    __shared__ float dtss[TS - 1];                 // ~4 KiB
    __shared__ __align__(16) float kbuf[2][16][4]; // ping-pong k accumulators

    const int tid  = threadIdx.x;
    const int lane = tid & 63;
    const int wv   = tid >> 6;       // 0..7
    const int nb   = lane & 15;      // batch row in tile
    const int g4   = lane >> 4;      // 0..3
    const int bb0  = blockIdx.x * 16;

    // loop-invariant LDS addresses (immediate offsets inside the loop)
    char* const wr = h1s + nb * ROWB + wv * 64 + g4 * 8;   // stage-A writes (+mt*32)
    char* const rd = h1s + nb * ROWB + g4 * 16;            // stage-B reads  (+ks*64)

    for (int i = tid; i < 768; i += 512) w3s[i] = W3g[i];
    for (int i = tid; i < TS - 1; i += 512) dtss[i] = tg[i + 1] - tg[i];
    if (tid < 128) ((float*)kbuf)[tid] = 0.f;

    const float b30 = b3g[0], b31 = b3g[1], b32 = b3g[2];
    float4 b2r0 = *(const float4*)&b2g[wv * 32 + g4 * 4];
    float4 b2r1 = *(const float4*)&b2g[wv * 32 + 16 + g4 * 4];

    // ---- per-thread RK4 state (redundant across the 32 threads sharing nb) ----
    float y00 = Ig[(bb0 + nb) * 3 + 0];
    float y01 = Ig[(bb0 + nb) * 3 + 1];
    float y02 = Ig[(bb0 + nb) * 3 + 2];
    float yc0 = y00, yc1 = y01, yc2 = y02;
    float ks0 = 0.f, ks1 = 0.f, ks2 = 0.f;
    if (tid < 16) {
        size_t o = (size_t)(bb0 + tid) * (TS * 3);
        outp[o + 0] = y00; outp[o + 1] = y01; outp[o + 2] = y02;
    }

    // ---- W2 persistent A-frags: A[m=ncol][k=h1col], swapped GEMM ----
    bf16x8 w2f[2][8];
    {
        const int ncb = wv * 32 + nb;
        #pragma unroll
        for (int mt = 0; mt < 2; ++mt) {
            #pragma unroll
            for (int ks = 0; ks < 8; ++ks) {
                FU f;
                #pragma unroll
                for (int jj = 0; jj < 4; ++jj) {
                    int k0 = ks * 32 + g4 * 8 + jj * 2;
                    f.u[jj] = cvt_pk(W2g[(size_t)k0 * 256 + ncb + mt * 16],
                                     W2g[(size_t)(k0 + 1) * 256 + ncb + mt * 16]);
                }
                w2f[mt][ks] = f.v;
            }
        }
    }

    // ---- W1 persistent A-frags, split precision + bias:
    //      k=0..2 W1h*yh, k=3..5 W1h*yl, k=6 b1 (g4==0); k=8..10 W1l*yh (g4==1) ----
    bf16x8 w1a[2];
    {
        #pragma unroll
        for (int mt = 0; mt < 2; ++mt) {
            const int col = (wv * 2 + mt) * 16 + nb;
            float w0 = W1g[col], w1 = W1g[256 + col], w2 = W1g[512 + col];
            float bb = b1g[col];
            FU f;
            if (g4 == 0) {
                f.u[0] = cvt_pk(w0, w1);
                f.u[1] = cvt_pk(w2, w0);
                f.u[2] = cvt_pk(w1, w2);
                f.u[3] = cvt_pk(bb, 0.f);
            } else if (g4 == 1) {
                unsigned int p01 = cvt_pk(w0, w1);
                unsigned int p2x = cvt_pk(w2, 0.f);
                float w0l = w0 - __uint_as_float(p01 << 16);
                float w1l = w1 - __uint_as_float(p01 & 0xFFFF0000u);
                float w2l = w2 - __uint_as_float(p2x << 16);
                f.u[0] = cvt_pk(w0l, w1l);
                f.u[1] = cvt_pk(w2l, 0.f);
                f.u[2] = 0u; f.u[3] = 0u;
            } else {
                f.u[0] = f.u[1] = f.u[2] = f.u[3] = 0u;
            }
            w1a[mt] = f.v;
        }
    }
    __syncthreads();

    for (int ev = 0; ev < NEV; ++ev) {
        // ---- combine previous eval's k (from LDS atomics); advance RK4 state ----
        if (ev > 0) {
            float4 kv = *(const float4*)&kbuf[ev & 1][nb][0];
            float k0 = kv.x + b30, k1 = kv.y + b31, k2 = kv.z + b32;
            float dtc = dtss[(ev - 1) >> 2];
            const int pph = (ev - 1) & 3;
            if (pph == 0) {
                ks0 = k0; ks1 = k1; ks2 = k2;
                float h = 0.5f * dtc;
                yc0 = fmaf(h, k0, y00); yc1 = fmaf(h, k1, y01); yc2 = fmaf(h, k2, y02);
            } else if (pph == 1) {
                ks0 += 2.f * k0; ks1 += 2.f * k1; ks2 += 2.f * k2;
                float h = 0.5f * dtc;
                yc0 = fmaf(h, k0, y00); yc1 = fmaf(h, k1, y01); yc2 = fmaf(h, k2, y02);
            } else if (pph == 2) {
                ks0 += 2.f * k0; ks1 += 2.f * k1; ks2 += 2.f * k2;
                yc0 = fmaf(dtc, k0, y00); yc1 = fmaf(dtc, k1, y01); yc2 = fmaf(dtc, k2, y02);
            } else {
                float s = dtc * (1.f / 6.f);
                y00 = fmaf(s, ks0 + k0, y00);
                y01 = fmaf(s, ks1 + k1, y01);
                y02 = fmaf(s, ks2 + k2, y02);
                yc0 = y00; yc1 = y01; yc2 = y02;
                const int t = ev >> 2;
                if (tid < 16) {
                    size_t o = (size_t)(bb0 + nb) * (TS * 3) + (size_t)t * 3;
                    outp[o + 0] = y00; outp[o + 1] = y01; outp[o + 2] = y02;
                }
            }
        }

        // ---- stage A: h1 via split-precision mfma; bf16 -> padded-row LDS ----
        {
            unsigned int u01  = cvt_pk(yc0, yc1);
            float yl0 = yc0 - __uint_as_float(u01 << 16);
            float yl1 = yc1 - __uint_as_float(u01 & 0xFFFF0000u);
            unsigned int u2l0 = cvt_pk(yc2, yl0);
            float yl2 = yc2 - __uint_as_float(u2l0 << 16);
            unsigned int ull  = cvt_pk(yl1, yl2);
            FU bf;
            if (g4 == 0) {
                bf.u[0] = u01; bf.u[1] = u2l0; bf.u[2] = ull; bf.u[3] = 0x00003f80u;
            } else if (g4 == 1) {
                bf.u[0] = u01; bf.u[1] = u2l0 & 0x0000FFFFu; bf.u[2] = 0u; bf.u[3] = 0u;
            } else {
                bf.u[0] = bf.u[1] = bf.u[2] = bf.u[3] = 0u;
            }
            #pragma unroll
            for (int mt = 0; mt < 2; ++mt) {
                f32x4 d = {0.f, 0.f, 0.f, 0.f};
                d = __builtin_amdgcn_mfma_f32_16x16x32_bf16(w1a[mt], bf.v, d, 0, 0, 0);
                uint2 wq;
                wq.x = cvt_pk(tanh_fast(d[0]), tanh_fast(d[1]));
                wq.y = cvt_pk(tanh_fast(d[2]), tanh_fast(d[3]));
                *(uint2*)(wr + mt * 32) = wq;
            }
        }
        __syncthreads();

        // ---- stage B: W2 mfma + tanh + W3 partials + atomic k-reduction ----
        {
            f32x4 acc0, acc1;
            acc0[0] = b2r0.x; acc0[1] = b2r0.y; acc0[2] = b2r0.z; acc0[3] = b2r0.w;
            acc1[0] = b2r1.x; acc1[1] = b2r1.y; acc1[2] = b2r1.z; acc1[3] = b2r1.w;
            #pragma unroll
            for (int ks = 0; ks < 8; ++ks) {
                FU tm; tm.q = *(const uint4*)(rd + ks * 64);
                acc0 = __builtin_amdgcn_mfma_f32_16x16x32_bf16(w2f[0][ks], tm.v, acc0, 0, 0, 0);
                acc1 = __builtin_amdgcn_mfma_f32_16x16x32_bf16(w2f[1][ks], tm.v, acc1, 0, 0, 0);
            }
            float p0 = 0.f, p1 = 0.f, p2 = 0.f;
            {
                const int row0 = wv * 32 + g4 * 4;
                float4 wa = *(const float4*)&w3s[row0 * 3];
                float4 wb = *(const float4*)&w3s[row0 * 3 + 4];
                float4 wc = *(const float4*)&w3s[row0 * 3 + 8];
                float h;
                h = tanh_fast(acc0[0]); p0 = fmaf(h, wa.x, p0); p1 = fmaf(h, wa.y, p1); p2 = fmaf(h, wa.z, p2);
                h = tanh_fast(acc0[1]); p0 = fmaf(h, wa.w, p0); p1 = fmaf(h, wb.x, p1); p2 = fmaf(h, wb.y, p2);
                h = tanh_fast(acc0[2]); p0 = fmaf(h, wb.z, p0); p1 = fmaf(h, wb.w, p1); p2 = fmaf(h, wc.x, p2);
                h = tanh_fast(acc0[3]); p0 = fmaf(h, wc.y, p0); p1 = fmaf(h, wc.z, p1); p2 = fmaf(h, wc.w, p2);
            }
            {
                const int row0 = wv * 32 + 16 + g4 * 4;
                float4 wa = *(const float4*)&w3s[row0 * 3];
                float4 wb = *(const float4*)&w3s[row0 * 3 + 4];
                float4 wc = *(const float4*)&w3s[row0 * 3 + 8];
                float h;
                h = tanh_fast(acc1[0]); p0 = fmaf(h, wa.x, p0); p1 = fmaf(h, wa.y, p1); p2 = fmaf(h, wa.z, p2);
                h = tanh_fast(acc1[1]); p0 = fmaf(h, wa.w, p0); p1 = fmaf(h, wb.x, p1); p2 = fmaf(h, wb.y, p2);
                h = tanh_fast(acc1[2]); p0 = fmaf(h, wb.z, p0); p1 = fmaf(h, wb.w, p1); p2 = fmaf(h, wc.x, p2);
                h = tanh_fast(acc1[3]); p0 = fmaf(h, wc.y, p0); p1 = fmaf(h, wc.z, p1); p2 = fmaf(h, wc.w, p2);
            }
            p0 += __shfl_xor(p0, 16); p1 += __shfl_xor(p1, 16); p2 += __shfl_xor(p2, 16);
            p0 += __shfl_xor(p0, 32); p1 += __shfl_xor(p1, 32); p2 += __shfl_xor(p2, 32);
            float* kw = &kbuf[(ev + 1) & 1][0][0];
            if (lane < 16) {
                atomicAdd(&kw[nb * 4 + 0], p0);
                atomicAdd(&kw[nb * 4 + 1], p1);
                atomicAdd(&kw[nb * 4 + 2], p2);
            }
            if (wv == 7) ((float*)&kbuf[ev & 1][0][0])[lane] = 0.f;  // retire old buf
        }
        __syncthreads();
    }

    // ---- tail: final k4 combine, write t = TS-1 ----
    {
        float4 kv = *(const float4*)&kbuf[NEV & 1][nb][0];
        float k0 = kv.x + b30, k1 = kv.y + b31, k2 = kv.z + b32;
        float dtc = dtss[(NEV - 1) >> 2];
        float s = dtc * (1.f / 6.f);
        y00 = fmaf(s, ks0 + k0, y00);
        y01 = fmaf(s, ks1 + k1, y01);
        y02 = fmaf(s, ks2 + k2, y02);
        if (tid < 16) {
            size_t o = (size_t)(bb0 + nb) * (TS * 3) + (size_t)(TS - 1) * 3;
            outp[o + 0] = y00; outp[o + 1] = y01; outp[o + 2] = y02;
        }
    }
}

extern "C" void kernel_launch(void* const* d_in, const int* in_sizes, int n_in,
                              void* d_out, int out_size, void* d_ws, size_t ws_size,
                              hipStream_t stream) {
    (void)in_sizes; (void)n_in; (void)d_ws; (void)ws_size; (void)out_size;
    const float* Ig  = (const float*)d_in[0];
    const float* tg  = (const float*)d_in[1];
    const float* W1g = (const float*)d_in[2];
    const float* b1g = (const float*)d_in[3];
    const float* W2g = (const float*)d_in[4];
    const float* b2g = (const float*)d_in[5];
    const float* W3g = (const float*)d_in[6];
    const float* b3g = (const float*)d_in[7];
    float* outp = (float*)d_out;

    dim3 grid(512), block(512);
    hipLaunchKernelGGL(node_ode_kernel, grid, block, 0, stream,
                       Ig, tg, W1g, b1g, W2g, b2g, W3g, b3g, outp);
}

// Round 4
// 9162.570 us; speedup vs baseline: 1.2227x; 1.2227x over previous
//
#include <hip/hip_runtime.h>

typedef __attribute__((ext_vector_type(8))) short bf16x8;
typedef __attribute__((ext_vector_type(4))) float f32x4;

union FU { unsigned int u[4]; uint4 q; bf16x8 v; };
union DF { double d; float f[2]; };

__device__ inline unsigned int cvt_pk(float lo, float hi) {
    unsigned int r;
    asm("v_cvt_pk_bf16_f32 %0, %1, %2" : "=v"(r) : "v"(lo), "v"(hi));
    return r;
}

__device__ inline double pk_add(double a, double b) {
    double r;
    asm("v_pk_add_f32 %0, %1, %2" : "=v"(r) : "v"(a), "v"(b));
    return r;
}

// tanh(x) = 1 - 2/(e^{2x}+1); inf/underflow saturate to +-1 correctly.
__device__ inline float tanh_fast(float x) {
    float e = __expf(x + x);
    return fmaf(-2.f, __builtin_amdgcn_rcpf(e + 1.f), 1.f);
}

#define TS 1000
#define NEV ((TS - 1) * 4)
#define ROWB 528   // 256 bf16 + 16B pad: loop-invariant base + imm offsets, 2-way banks

// 512 threads = 8 waves own 16 batch rows for the whole rollout.
// Per eval: [combine prev k: 6 LDS reads + pk_add tree; RK4 in regs]
//           [stage A: h1 = tanh(W1aug @ [yh;yl;1]) via 2 mfma -> LDS bf16 padded rows]
//           barrier
//           [stage B: h2pre = W2^T.h1^T + b2 via 16 mfma (imm-offset ds_reads);
//            tanh; W3 partials (float4/channel table); shfl reduce; 2 ds writes]
//           barrier
__global__ __launch_bounds__(512, 4)
void node_ode_kernel(const float* __restrict__ Ig, const float* __restrict__ tg,
                     const float* __restrict__ W1g, const float* __restrict__ b1g,
                     const float* __restrict__ W2g, const float* __restrict__ b2g,
                     const float* __restrict__ W3g, const float* __restrict__ b3g,
                     float* __restrict__ outp)
{
    __shared__ __align__(16) char h1s[16 * ROWB];   // 8448 B
    __shared__ __align__(16) float4 w3p[256];       // 4 KiB: (w0,w1,w2,0) per channel
    __shared__ float b2s[256];                      // 1 KiB
    __shared__ float dtss[TS - 1];                  // ~4 KiB
    __shared__ __align__(16) char part2[16 * 112];  // per nb: 8 dbl (p0,p1) + 8 f32 p2 + pad

    const int tid  = threadIdx.x;
    const int lane = tid & 63;
    const int wv   = tid >> 6;       // 0..7
    const int nb   = lane & 15;      // batch row in tile
    const int g4   = lane >> 4;      // 0..3
    const int bb0  = blockIdx.x * 16;

    // loop-invariant LDS bases (immediate offsets inside the loop)
    char* const wr        = h1s + nb * ROWB + wv * 64 + g4 * 8;      // A-writes (+mt*32)
    const char* const rd  = h1s + nb * ROWB + g4 * 16;               // B-reads  (+ks*64)
    const char* const w3b = (const char*)w3p + (wv * 32 + g4 * 4) * 16; // (+mt*256 +r*16)
    const char* const b2b = (const char*)b2s + wv * 128 + g4 * 16;   // (+64)
    const char* const prd = part2 + nb * 112;
    char* const pwr       = part2 + nb * 112 + wv * 8;

    if (tid < 256) {
        w3p[tid] = make_float4(W3g[tid * 3], W3g[tid * 3 + 1], W3g[tid * 3 + 2], 0.f);
        b2s[tid] = b2g[tid];
    }
    for (int i = tid; i < TS - 1; i += 512) dtss[i] = tg[i + 1] - tg[i];

    const float b30 = b3g[0], b31 = b3g[1], b32 = b3g[2];

    // ---- per-thread RK4 state (redundant across the 32 threads sharing nb) ----
    float y00 = Ig[(bb0 + nb) * 3 + 0];
    float y01 = Ig[(bb0 + nb) * 3 + 1];
    float y02 = Ig[(bb0 + nb) * 3 + 2];
    float yc0 = y00, yc1 = y01, yc2 = y02;
    float ks0 = 0.f, ks1 = 0.f, ks2 = 0.f;
    if (tid < 16) {
        size_t o = (size_t)(bb0 + tid) * (TS * 3);
        outp[o + 0] = y00; outp[o + 1] = y01; outp[o + 2] = y02;
    }

    // ---- W2 persistent A-frags: A[m=ncol][k=h1col], swapped GEMM ----
    bf16x8 w2f[2][8];
    {
        const int ncb = wv * 32 + nb;
        #pragma unroll
        for (int mt = 0; mt < 2; ++mt) {
            #pragma unroll
            for (int ks = 0; ks < 8; ++ks) {
                FU f;
                #pragma unroll
                for (int jj = 0; jj < 4; ++jj) {
                    int k0 = ks * 32 + g4 * 8 + jj * 2;
                    f.u[jj] = cvt_pk(W2g[(size_t)k0 * 256 + ncb + mt * 16],
                                     W2g[(size_t)(k0 + 1) * 256 + ncb + mt * 16]);
                }
                w2f[mt][ks] = f.v;
            }
        }
    }

    // ---- W1 persistent A-frags, split precision + bias:
    //      k=0..2 W1h*yh, k=3..5 W1h*yl, k=6 b1 (g4==0); k=8..10 W1l*yh (g4==1) ----
    bf16x8 w1a[2];
    {
        #pragma unroll
        for (int mt = 0; mt < 2; ++mt) {
            const int col = (wv * 2 + mt) * 16 + nb;
            float w0 = W1g[col], w1 = W1g[256 + col], w2 = W1g[512 + col];
            float bb = b1g[col];
            FU f;
            if (g4 == 0) {
                f.u[0] = cvt_pk(w0, w1);
                f.u[1] = cvt_pk(w2, w0);
                f.u[2] = cvt_pk(w1, w2);
                f.u[3] = cvt_pk(bb, 0.f);
            } else if (g4 == 1) {
                unsigned int p01 = cvt_pk(w0, w1);
                unsigned int p2x = cvt_pk(w2, 0.f);
                float w0l = w0 - __uint_as_float(p01 << 16);
                float w1l = w1 - __uint_as_float(p01 & 0xFFFF0000u);
                float w2l = w2 - __uint_as_float(p2x << 16);
                f.u[0] = cvt_pk(w0l, w1l);
                f.u[1] = cvt_pk(w2l, 0.f);
                f.u[2] = 0u; f.u[3] = 0u;
            } else {
                f.u[0] = f.u[1] = f.u[2] = f.u[3] = 0u;
            }
            w1a[mt] = f.v;
        }
    }
    __syncthreads();

    for (int ev = 0; ev < NEV; ++ev) {
        // ---- combine previous eval's k (pk_add tree); advance RK4 state ----
        if (ev > 0) {
            double2 a = *(const double2*)(prd + 0);
            double2 b = *(const double2*)(prd + 16);
            double2 c = *(const double2*)(prd + 32);
            double2 d = *(const double2*)(prd + 48);
            DF u;
            u.d = pk_add(pk_add(pk_add(a.x, a.y), pk_add(b.x, b.y)),
                         pk_add(pk_add(c.x, c.y), pk_add(d.x, d.y)));
            float k0 = u.f[0] + b30;
            float k1 = u.f[1] + b31;
            float4 r0 = *(const float4*)(prd + 64);
            float4 r1 = *(const float4*)(prd + 80);
            float k2 = (((r0.x + r0.y) + (r0.z + r0.w)) +
                        ((r1.x + r1.y) + (r1.z + r1.w))) + b32;
            float dtc = dtss[(ev - 1) >> 2];
            const int pph = (ev - 1) & 3;
            if (pph == 0) {
                ks0 = k0; ks1 = k1; ks2 = k2;
                float h = 0.5f * dtc;
                yc0 = fmaf(h, k0, y00); yc1 = fmaf(h, k1, y01); yc2 = fmaf(h, k2, y02);
            } else if (pph == 1) {
                ks0 += 2.f * k0; ks1 += 2.f * k1; ks2 += 2.f * k2;
                float h = 0.5f * dtc;
                yc0 = fmaf(h, k0, y00); yc1 = fmaf(h, k1, y01); yc2 = fmaf(h, k2, y02);
            } else if (pph == 2) {
                ks0 += 2.f * k0; ks1 += 2.f * k1; ks2 += 2.f * k2;
                yc0 = fmaf(dtc, k0, y00); yc1 = fmaf(dtc, k1, y01); yc2 = fmaf(dtc, k2, y02);
            } else {
                float s = dtc * (1.f / 6.f);
                y00 = fmaf(s, ks0 + k0, y00);
                y01 = fmaf(s, ks1 + k1, y01);
                y02 = fmaf(s, ks2 + k2, y02);
                yc0 = y00; yc1 = y01; yc2 = y02;
                const int t = ev >> 2;
                if (tid < 16) {
                    size_t o = (size_t)(bb0 + nb) * (TS * 3) + (size_t)t * 3;
                    outp[o + 0] = y00; outp[o + 1] = y01; outp[o + 2] = y02;
                }
            }
        }

        // ---- stage A: h1 via split-precision mfma; bf16 -> padded-row LDS ----
        {
            unsigned int u01  = cvt_pk(yc0, yc1);
            float yl0 = yc0 - __uint_as_float(u01 << 16);
            float yl1 = yc1 - __uint_as_float(u01 & 0xFFFF0000u);
            unsigned int u2l0 = cvt_pk(yc2, yl0);
            float yl2 = yc2 - __uint_as_float(u2l0 << 16);
            unsigned int ull  = cvt_pk(yl1, yl2);
            FU bf;
            if (g4 == 0) {
                bf.u[0] = u01; bf.u[1] = u2l0; bf.u[2] = ull; bf.u[3] = 0x00003f80u;
            } else if (g4 == 1) {
                bf.u[0] = u01; bf.u[1] = u2l0 & 0x0000FFFFu; bf.u[2] = 0u; bf.u[3] = 0u;
            } else {
                bf.u[0] = bf.u[1] = bf.u[2] = bf.u[3] = 0u;
            }
            #pragma unroll
            for (int mt = 0; mt < 2; ++mt) {
                f32x4 d = {0.f, 0.f, 0.f, 0.f};
                d = __builtin_amdgcn_mfma_f32_16x16x32_bf16(w1a[mt], bf.v, d, 0, 0, 0);
                uint2 wq;
                wq.x = cvt_pk(tanh_fast(d[0]), tanh_fast(d[1]));
                wq.y = cvt_pk(tanh_fast(d[2]), tanh_fast(d[3]));
                *(uint2*)(wr + mt * 32) = wq;
            }
        }
        __syncthreads();

        // ---- stage B: W2 mfma + tanh + W3 partials + shfl reduce ----
        {
            f32x4 acc0, acc1;
            {
                float4 t0 = *(const float4*)(b2b);
                float4 t1 = *(const float4*)(b2b + 64);
                acc0[0] = t0.x; acc0[1] = t0.y; acc0[2] = t0.z; acc0[3] = t0.w;
                acc1[0] = t1.x; acc1[1] = t1.y; acc1[2] = t1.z; acc1[3] = t1.w;
            }
            #pragma unroll
            for (int ks = 0; ks < 8; ++ks) {
                FU tm; tm.q = *(const uint4*)(rd + ks * 64);
                acc0 = __builtin_amdgcn_mfma_f32_16x16x32_bf16(w2f[0][ks], tm.v, acc0, 0, 0, 0);
                acc1 = __builtin_amdgcn_mfma_f32_16x16x32_bf16(w2f[1][ks], tm.v, acc1, 0, 0, 0);
            }
            float p0 = 0.f, p1 = 0.f, p2 = 0.f;
            #pragma unroll
            for (int r = 0; r < 4; ++r) {
                float4 w = *(const float4*)(w3b + r * 16);
                float h = tanh_fast(acc0[r]);
                p0 = fmaf(h, w.x, p0); p1 = fmaf(h, w.y, p1); p2 = fmaf(h, w.z, p2);
            }
            #pragma unroll
            for (int r = 0; r < 4; ++r) {
                float4 w = *(const float4*)(w3b + 256 + r * 16);
                float h = tanh_fast(acc1[r]);
                p0 = fmaf(h, w.x, p0); p1 = fmaf(h, w.y, p1); p2 = fmaf(h, w.z, p2);
            }
            p0 += __shfl_xor(p0, 16); p1 += __shfl_xor(p1, 16); p2 += __shfl_xor(p2, 16);
            p0 += __shfl_xor(p0, 32); p1 += __shfl_xor(p1, 32); p2 += __shfl_xor(p2, 32);
            if (lane < 16) {
                DF w; w.f[0] = p0; w.f[1] = p1;
                *(double*)(pwr) = w.d;
                *(float*)(part2 + nb * 112 + 64 + wv * 4) = p2;
            }
        }
        __syncthreads();
    }

    // ---- tail: final k4 combine, write t = TS-1 ----
    {
        double2 a = *(const double2*)(prd + 0);
        double2 b = *(const double2*)(prd + 16);
        double2 c = *(const double2*)(prd + 32);
        double2 d = *(const double2*)(prd + 48);
        DF u;
        u.d = pk_add(pk_add(pk_add(a.x, a.y), pk_add(b.x, b.y)),
                     pk_add(pk_add(c.x, c.y), pk_add(d.x, d.y)));
        float k0 = u.f[0] + b30;
        float k1 = u.f[1] + b31;
        float4 r0 = *(const float4*)(prd + 64);
        float4 r1 = *(const float4*)(prd + 80);
        float k2 = (((r0.x + r0.y) + (r0.z + r0.w)) +
                    ((r1.x + r1.y) + (r1.z + r1.w))) + b32;
        float dtc = dtss[(NEV - 1) >> 2];
        float s = dtc * (1.f / 6.f);
        y00 = fmaf(s, ks0 + k0, y00);
        y01 = fmaf(s, ks1 + k1, y01);
        y02 = fmaf(s, ks2 + k2, y02);
        if (tid < 16) {
            size_t o = (size_t)(bb0 + nb) * (TS * 3) + (size_t)(TS - 1) * 3;
            outp[o + 0] = y00; outp[o + 1] = y01; outp[o + 2] = y02;
        }
    }
}

extern "C" void kernel_launch(void* const* d_in, const int* in_sizes, int n_in,
                              void* d_out, int out_size, void* d_ws, size_t ws_size,
                              hipStream_t stream) {
    (void)in_sizes; (void)n_in; (void)d_ws; (void)ws_size; (void)out_size;
    const float* Ig  = (const float*)d_in[0];
    const float* tg  = (const float*)d_in[1];
    const float* W1g = (const float*)d_in[2];
    const float* b1g = (const float*)d_in[3];
    const float* W2g = (const float*)d_in[4];
    const float* b2g = (const float*)d_in[5];
    const float* W3g = (const float*)d_in[6];
    const float* b3g = (const float*)d_in[7];
    float* outp = (float*)d_out;

    dim3 grid(512), block(512);
    hipLaunchKernelGGL(node_ode_kernel, grid, block, 0, stream,
                       Ig, tg, W1g, b1g, W2g, b2g, W3g, b3g, outp);
}